// Round 1
// baseline (4551.686 us; speedup 1.0000x reference)
//
#include <hip/hip_runtime.h>

#define NNODES 100000
#define NEDGES 1600000
#define ETOT   1700000   // NEDGES + NNODES self-loops
#define NGRAPH 64
#define NEG    0.2f

__device__ __forceinline__ float f4get(const float4& v, int j) {
    return j == 0 ? v.x : j == 1 ? v.y : j == 2 ? v.z : v.w;
}

__device__ __forceinline__ void edge_sd(const int* __restrict__ ei, int e, int& s, int& d) {
    if (e < NEDGES) { s = ei[e]; d = ei[NEDGES + e]; }
    else            { s = d = e - NEDGES; }
}

// ---------------- GEMM1: h1[N,128] = x[N,128] @ W1[128,128] ----------------
__global__ __launch_bounds__(256) void k_gemm1(const float* __restrict__ x,
                                               const float* __restrict__ W1,
                                               float* __restrict__ h1) {
    __shared__ float sW[128 * 128];   // 64 KB
    __shared__ float sX[64 * 128];    // 32 KB
    int t = threadIdx.x;
    {
        const float4* W4 = (const float4*)W1;
        float4* sW4 = (float4*)sW;
#pragma unroll
        for (int i = 0; i < 16; ++i) sW4[t + 256 * i] = W4[t + 256 * i];
    }
    int nbase = blockIdx.x * 64;
    int nrows = NNODES - nbase; if (nrows > 64) nrows = 64;
    {
        const float4* X4 = (const float4*)(x + (size_t)nbase * 128);
        float4* sX4 = (float4*)sX;
        for (int i = t; i < nrows * 32; i += 256) sX4[i] = X4[i];
    }
    __syncthreads();

    int colg = t & 31, rowg = t >> 5;
    int c0 = colg * 4, n0 = rowg * 8;
    float acc[8][4];
#pragma unroll
    for (int i = 0; i < 8; ++i)
        acc[i][0] = acc[i][1] = acc[i][2] = acc[i][3] = 0.f;

    for (int k = 0; k < 128; k += 4) {
        float4 w0 = *(const float4*)&sW[(k + 0) * 128 + c0];
        float4 w1 = *(const float4*)&sW[(k + 1) * 128 + c0];
        float4 w2 = *(const float4*)&sW[(k + 2) * 128 + c0];
        float4 w3 = *(const float4*)&sW[(k + 3) * 128 + c0];
#pragma unroll
        for (int i = 0; i < 8; ++i) {
            float4 xv = *(const float4*)&sX[(n0 + i) * 128 + k];
            acc[i][0] = fmaf(xv.x, w0.x, acc[i][0]); acc[i][1] = fmaf(xv.x, w0.y, acc[i][1]);
            acc[i][2] = fmaf(xv.x, w0.z, acc[i][2]); acc[i][3] = fmaf(xv.x, w0.w, acc[i][3]);
            acc[i][0] = fmaf(xv.y, w1.x, acc[i][0]); acc[i][1] = fmaf(xv.y, w1.y, acc[i][1]);
            acc[i][2] = fmaf(xv.y, w1.z, acc[i][2]); acc[i][3] = fmaf(xv.y, w1.w, acc[i][3]);
            acc[i][0] = fmaf(xv.z, w2.x, acc[i][0]); acc[i][1] = fmaf(xv.z, w2.y, acc[i][1]);
            acc[i][2] = fmaf(xv.z, w2.z, acc[i][2]); acc[i][3] = fmaf(xv.z, w2.w, acc[i][3]);
            acc[i][0] = fmaf(xv.w, w3.x, acc[i][0]); acc[i][1] = fmaf(xv.w, w3.y, acc[i][1]);
            acc[i][2] = fmaf(xv.w, w3.z, acc[i][2]); acc[i][3] = fmaf(xv.w, w3.w, acc[i][3]);
        }
    }
#pragma unroll
    for (int i = 0; i < 8; ++i) {
        int n = n0 + i;
        if (n < nrows) {
            float4 st = make_float4(acc[i][0], acc[i][1], acc[i][2], acc[i][3]);
            *(float4*)&h1[((size_t)(nbase + n)) * 128 + c0] = st;
        }
    }
}

// -------- per-node attention logits layer 1: (node, head) per thread --------
__global__ void k_alphas1(const float* __restrict__ h1, const float* __restrict__ a_s,
                          const float* __restrict__ a_d,
                          float* __restrict__ as1, float* __restrict__ ad1) {
    int t = blockIdx.x * 256 + threadIdx.x;
    if (t >= NNODES * 4) return;
    int n = t >> 2, h = t & 3;
    const float4* hp = (const float4*)(h1 + (size_t)n * 128 + h * 32);
    const float4* sp = (const float4*)(a_s + h * 32);
    const float4* dp = (const float4*)(a_d + h * 32);
    float ss = 0.f, sd = 0.f;
#pragma unroll
    for (int i = 0; i < 8; ++i) {
        float4 hv = hp[i], av = sp[i], bv = dp[i];
        ss += hv.x * av.x + hv.y * av.y + hv.z * av.z + hv.w * av.w;
        sd += hv.x * bv.x + hv.y * bv.y + hv.z * bv.z + hv.w * bv.w;
    }
    as1[t] = ss; ad1[t] = sd;
}

// -------- edge pass 1a: denom1[d,h] += exp(leaky(as[s,h]+ad[d,h])) --------
__global__ void k_edge1a(const int* __restrict__ ei, const float* __restrict__ as1,
                         const float* __restrict__ ad1, float* __restrict__ denom1) {
    int e = blockIdx.x * 256 + threadIdx.x;
    if (e >= ETOT) return;
    int s, d; edge_sd(ei, e, s, d);
    float4 av = *(const float4*)(as1 + (size_t)s * 4);
    float4 bv = *(const float4*)(ad1 + (size_t)d * 4);
    float v;
    v = av.x + bv.x; v = v > 0.f ? v : NEG * v; unsafeAtomicAdd(&denom1[d * 4 + 0], __expf(v));
    v = av.y + bv.y; v = v > 0.f ? v : NEG * v; unsafeAtomicAdd(&denom1[d * 4 + 1], __expf(v));
    v = av.z + bv.z; v = v > 0.f ? v : NEG * v; unsafeAtomicAdd(&denom1[d * 4 + 2], __expf(v));
    v = av.w + bv.w; v = v > 0.f ? v : NEG * v; unsafeAtomicAdd(&denom1[d * 4 + 3], __expf(v));
}

// -------- edge pass 1b: out1[d,:] += alpha * h1[s,:]  (32 threads/edge) ----
__global__ __launch_bounds__(256) void k_edge1b(const int* __restrict__ ei,
        const float* __restrict__ h1, const float* __restrict__ as1,
        const float* __restrict__ ad1, const float* __restrict__ denom1,
        float* __restrict__ out1) {
    unsigned t = blockIdx.x * 256u + threadIdx.x;
    unsigned e = t >> 5;
    if (e >= ETOT) return;
    int part = (int)(t & 31u);
    int s, d; edge_sd(ei, (int)e, s, d);
    int head = part >> 3;
    float v = as1[s * 4 + head] + ad1[d * 4 + head];
    v = v > 0.f ? v : NEG * v;
    float alpha = __expf(v) / denom1[d * 4 + head];
    float4 hv = *(const float4*)(h1 + (size_t)s * 128 + part * 4);
    float* op = out1 + (size_t)d * 128 + part * 4;
    unsafeAtomicAdd(op + 0, hv.x * alpha);
    unsafeAtomicAdd(op + 1, hv.y * alpha);
    unsafeAtomicAdd(op + 2, hv.z * alpha);
    unsafeAtomicAdd(op + 3, hv.w * alpha);
}

// ---- GEMM2: h2[N,40] = ELU(out1 + b1) @ W2[128,40] ----
__global__ __launch_bounds__(256) void k_gemm2(const float* __restrict__ in,
                                               const float* __restrict__ W2,
                                               const float* __restrict__ b1,
                                               float* __restrict__ h2) {
    __shared__ float sW[128 * 40];    // 20 KB
    __shared__ float sX[128 * 132];   // padded rows: 132 floats (bank-safe, 16B-aligned)
    int t = threadIdx.x;
    for (int i = t; i < 128 * 40 / 4; i += 256) ((float4*)sW)[i] = ((const float4*)W2)[i];
    int nbase = blockIdx.x * 128;
    int nrows = NNODES - nbase; if (nrows > 128) nrows = 128;
    {
        const float4* X4 = (const float4*)(in + (size_t)nbase * 128);
        for (int i = t; i < nrows * 32; i += 256) {
            int row = i >> 5, c4 = i & 31;
            float4 v = X4[i];
            float4 bb = *(const float4*)&b1[c4 * 4];
            v.x += bb.x; v.y += bb.y; v.z += bb.z; v.w += bb.w;
            v.x = v.x > 0.f ? v.x : __expf(v.x) - 1.f;
            v.y = v.y > 0.f ? v.y : __expf(v.y) - 1.f;
            v.z = v.z > 0.f ? v.z : __expf(v.z) - 1.f;
            v.w = v.w > 0.f ? v.w : __expf(v.w) - 1.f;
            *(float4*)&sX[row * 132 + c4 * 4] = v;
        }
    }
    __syncthreads();

    int colg = t & 7, nodeg = t >> 3;
    int c0 = colg * 5;
    float acc[4][5];
#pragma unroll
    for (int i = 0; i < 4; ++i)
#pragma unroll
        for (int c = 0; c < 5; ++c) acc[i][c] = 0.f;

    for (int k = 0; k < 128; k += 4) {
        float4 xv[4];
#pragma unroll
        for (int i = 0; i < 4; ++i)
            xv[i] = *(const float4*)&sX[(nodeg + 32 * i) * 132 + k];
#pragma unroll
        for (int j = 0; j < 4; ++j) {
            float w0 = sW[(k + j) * 40 + c0 + 0];
            float w1 = sW[(k + j) * 40 + c0 + 1];
            float w2 = sW[(k + j) * 40 + c0 + 2];
            float w3 = sW[(k + j) * 40 + c0 + 3];
            float w4 = sW[(k + j) * 40 + c0 + 4];
#pragma unroll
            for (int i = 0; i < 4; ++i) {
                float xs = f4get(xv[i], j);
                acc[i][0] = fmaf(xs, w0, acc[i][0]);
                acc[i][1] = fmaf(xs, w1, acc[i][1]);
                acc[i][2] = fmaf(xs, w2, acc[i][2]);
                acc[i][3] = fmaf(xs, w3, acc[i][3]);
                acc[i][4] = fmaf(xs, w4, acc[i][4]);
            }
        }
    }
#pragma unroll
    for (int i = 0; i < 4; ++i) {
        int n = nodeg + 32 * i;
        if (n < nrows) {
            float* op = h2 + (size_t)(nbase + n) * 40 + c0;
#pragma unroll
            for (int c = 0; c < 5; ++c) op[c] = acc[i][c];
        }
    }
}

// -------- per-node attention logits layer 2 --------
__global__ void k_alphas2(const float* __restrict__ h2, const float* __restrict__ a_s,
                          const float* __restrict__ a_d,
                          float* __restrict__ as2, float* __restrict__ ad2) {
    int n = blockIdx.x * 256 + threadIdx.x;
    if (n >= NNODES) return;
    const float4* hp = (const float4*)(h2 + (size_t)n * 40);
    float ss = 0.f, sd = 0.f;
#pragma unroll
    for (int i = 0; i < 10; ++i) {
        float4 hv = hp[i];
        float4 av = ((const float4*)a_s)[i];
        float4 bv = ((const float4*)a_d)[i];
        ss += hv.x * av.x + hv.y * av.y + hv.z * av.z + hv.w * av.w;
        sd += hv.x * bv.x + hv.y * bv.y + hv.z * bv.z + hv.w * bv.w;
    }
    as2[n] = ss; ad2[n] = sd;
}

__global__ void k_edge2a(const int* __restrict__ ei, const float* __restrict__ as2,
                         const float* __restrict__ ad2, float* __restrict__ denom2) {
    int e = blockIdx.x * 256 + threadIdx.x;
    if (e >= ETOT) return;
    int s, d; edge_sd(ei, e, s, d);
    float v = as2[s] + ad2[d];
    v = v > 0.f ? v : NEG * v;
    unsafeAtomicAdd(&denom2[d], __expf(v));
}

// -------- edge pass 2b: 10 threads/edge (40 ch as 10 float4) --------
__global__ __launch_bounds__(320) void k_edge2b(const int* __restrict__ ei,
        const float* __restrict__ h2, const float* __restrict__ as2,
        const float* __restrict__ ad2, const float* __restrict__ denom2,
        float* __restrict__ out2) {
    unsigned t = blockIdx.x * 320u + threadIdx.x;
    unsigned e = t / 10u;
    if (e >= ETOT) return;
    int q = (int)(t - e * 10u);
    int s, d; edge_sd(ei, (int)e, s, d);
    float v = as2[s] + ad2[d];
    v = v > 0.f ? v : NEG * v;
    float alpha = __expf(v) / denom2[d];
    float4 hv = *(const float4*)(h2 + (size_t)s * 40 + q * 4);
    float* op = out2 + (size_t)d * 40 + q * 4;
    unsafeAtomicAdd(op + 0, hv.x * alpha);
    unsafeAtomicAdd(op + 1, hv.y * alpha);
    unsafeAtomicAdd(op + 2, hv.z * alpha);
    unsafeAtomicAdd(op + 3, hv.w * alpha);
}

// -------- global mean pool: one block per graph, binary search on sorted batch ----
__global__ __launch_bounds__(256) void k_pool(const float* __restrict__ out2,
        const int* __restrict__ batch, const float* __restrict__ b2,
        float* __restrict__ out) {
    int g = blockIdx.x;
    int lo, hi;
    { int a = 0, b = NNODES; while (a < b) { int m = (a + b) >> 1; if (batch[m] < g) a = m + 1; else b = m; } lo = a; }
    { int a = lo, b = NNODES; while (a < b) { int m = (a + b) >> 1; if (batch[m] < g + 1) a = m + 1; else b = m; } hi = a; }
    int cnt = hi - lo;
    int t = threadIdx.x;
    float sum = 0.f;
    if (t < 240) {
        int c = t % 40, r = t / 40;
        for (int n = lo + r; n < hi; n += 6) sum += out2[(size_t)n * 40 + c];
    }
    __shared__ float red[240];
    if (t < 240) red[t] = sum;
    __syncthreads();
    if (t < 40) {
        float s2 = red[t] + red[t + 40] + red[t + 80] + red[t + 120] + red[t + 160] + red[t + 200];
        out[g * 40 + t] = cnt > 0 ? (s2 / (float)cnt + b2[t]) : 0.f;
    }
}

extern "C" void kernel_launch(void* const* d_in, const int* in_sizes, int n_in,
                              void* d_out, int out_size, void* d_ws, size_t ws_size,
                              hipStream_t stream) {
    const float* x    = (const float*)d_in[0];
    const int*   ei   = (const int*)d_in[1];
    const int*   batch= (const int*)d_in[2];
    const float* W1   = (const float*)d_in[3];
    const float* a1s  = (const float*)d_in[4];
    const float* a1d  = (const float*)d_in[5];
    const float* b1   = (const float*)d_in[6];
    const float* W2   = (const float*)d_in[7];
    const float* a2s  = (const float*)d_in[8];
    const float* a2d  = (const float*)d_in[9];
    const float* b2   = (const float*)d_in[10];
    float* out = (float*)d_out;

    // workspace layout: zero-init region first (one memset), then scratch
    float* denom1 = (float*)d_ws;                          // N*4
    float* out1   = denom1 + (size_t)NNODES * 4;           // N*128
    float* denom2 = out1   + (size_t)NNODES * 128;         // N
    float* out2   = denom2 + (size_t)NNODES;               // N*40
    float* h1     = out2   + (size_t)NNODES * 40;          // N*128
    float* as1    = h1     + (size_t)NNODES * 128;         // N*4
    float* ad1    = as1    + (size_t)NNODES * 4;           // N*4
    float* h2     = ad1    + (size_t)NNODES * 4;           // N*40
    float* as2    = h2     + (size_t)NNODES * 40;          // N
    float* ad2    = as2    + (size_t)NNODES;               // N

    size_t zero_floats = (size_t)NNODES * (4 + 128 + 1 + 40);
    hipMemsetAsync(d_ws, 0, zero_floats * sizeof(float), stream);

    k_gemm1<<<(NNODES + 63) / 64, 256, 0, stream>>>(x, W1, h1);
    k_alphas1<<<(NNODES * 4 + 255) / 256, 256, 0, stream>>>(h1, a1s, a1d, as1, ad1);
    k_edge1a<<<(ETOT + 255) / 256, 256, 0, stream>>>(ei, as1, ad1, denom1);
    {
        unsigned total = (unsigned)ETOT * 32u;
        k_edge1b<<<(total + 255) / 256, 256, 0, stream>>>(ei, h1, as1, ad1, denom1, out1);
    }
    k_gemm2<<<(NNODES + 127) / 128, 256, 0, stream>>>(out1, W2, b1, h2);
    k_alphas2<<<(NNODES + 255) / 256, 256, 0, stream>>>(h2, a2s, a2d, as2, ad2);
    k_edge2a<<<(ETOT + 255) / 256, 256, 0, stream>>>(ei, as2, ad2, denom2);
    {
        unsigned total = (unsigned)ETOT * 10u;
        k_edge2b<<<(total + 319) / 320, 320, 0, stream>>>(ei, h2, as2, ad2, denom2, out2);
    }
    k_pool<<<NGRAPH, 256, 0, stream>>>(out2, batch, b2, out);
}

// Round 3
// 674.514 us; speedup vs baseline: 6.7481x; 6.7481x over previous
//
#include <hip/hip_runtime.h>

#define NNODES 100000
#define NEDGES 1600000
#define ETOT   1700000   // NEDGES + NNODES self-loops
#define NGRAPH 64
#define NEG    0.2f
#define NB_SCAN 98       // ceil(NNODES / 1024)

__device__ __forceinline__ float f4get(const float4& v, int j) {
    return j == 0 ? v.x : j == 1 ? v.y : j == 2 ? v.z : v.w;
}

__device__ __forceinline__ void edge_sd(const int* __restrict__ ei, int e, int& s, int& d) {
    if (e < NEDGES) { s = ei[e]; d = ei[NEDGES + e]; }
    else            { s = d = e - NEDGES; }
}

// ======================= CSR build (per call, deterministic work) =======================
__global__ void k_hist(const int* __restrict__ ei, int* __restrict__ cnt) {
    int e = blockIdx.x * 256 + threadIdx.x;
    if (e >= ETOT) return;
    int s, d; edge_sd(ei, e, s, d);
    atomicAdd(&cnt[d], 1);
}

// level-1 scan: 1024 elems/block (256 thr x 4), exclusive within block + block sums
__global__ __launch_bounds__(256) void k_scan1(const int* __restrict__ cnt,
                                               int* __restrict__ excl,
                                               int* __restrict__ bsum) {
    __shared__ int tmp[256];
    int t = threadIdx.x;
    int base = blockIdx.x * 1024 + t * 4;
    int v0 = base + 0 < NNODES ? cnt[base + 0] : 0;
    int v1 = base + 1 < NNODES ? cnt[base + 1] : 0;
    int v2 = base + 2 < NNODES ? cnt[base + 2] : 0;
    int v3 = base + 3 < NNODES ? cnt[base + 3] : 0;
    int tot = v0 + v1 + v2 + v3;
    tmp[t] = tot;
    __syncthreads();
    for (int off = 1; off < 256; off <<= 1) {
        int x = (t >= off) ? tmp[t - off] : 0;
        __syncthreads();
        tmp[t] += x;
        __syncthreads();
    }
    int tbase = tmp[t] - tot;  // exclusive prefix of this thread's 4
    if (base + 0 < NNODES) excl[base + 0] = tbase;
    if (base + 1 < NNODES) excl[base + 1] = tbase + v0;
    if (base + 2 < NNODES) excl[base + 2] = tbase + v0 + v1;
    if (base + 3 < NNODES) excl[base + 3] = tbase + v0 + v1 + v2;
    if (t == 255) bsum[blockIdx.x] = tmp[255];
}

// level-2: serial exclusive scan of NB_SCAN block sums (tiny)
__global__ void k_scan2(int* __restrict__ bsum) {
    if (threadIdx.x == 0 && blockIdx.x == 0) {
        int acc = 0;
        for (int i = 0; i < NB_SCAN; ++i) { int v = bsum[i]; bsum[i] = acc; acc += v; }
    }
}

__global__ void k_scatter(const int* __restrict__ ei, const int* __restrict__ excl,
                          const int* __restrict__ bsum, int* __restrict__ cursor,
                          int* __restrict__ csr_src) {
    int e = blockIdx.x * 256 + threadIdx.x;
    if (e >= ETOT) return;
    int s, d; edge_sd(ei, e, s, d);
    int pos = excl[d] + bsum[d >> 10] + atomicAdd(&cursor[d], 1);
    csr_src[pos] = s;
}

// ---------------- GEMM1: h1[N,128] = x[N,128] @ W1[128,128] ----------------
__global__ __launch_bounds__(256) void k_gemm1(const float* __restrict__ x,
                                               const float* __restrict__ W1,
                                               float* __restrict__ h1) {
    __shared__ float sW[128 * 128];   // 64 KB
    __shared__ float sX[64 * 128];    // 32 KB
    int t = threadIdx.x;
    {
        const float4* W4 = (const float4*)W1;
        float4* sW4 = (float4*)sW;
#pragma unroll
        for (int i = 0; i < 16; ++i) sW4[t + 256 * i] = W4[t + 256 * i];
    }
    int nbase = blockIdx.x * 64;
    int nrows = NNODES - nbase; if (nrows > 64) nrows = 64;
    {
        const float4* X4 = (const float4*)(x + (size_t)nbase * 128);
        float4* sX4 = (float4*)sX;
        for (int i = t; i < nrows * 32; i += 256) sX4[i] = X4[i];
    }
    __syncthreads();

    int colg = t & 31, rowg = t >> 5;
    int c0 = colg * 4, n0 = rowg * 8;
    float acc[8][4];
#pragma unroll
    for (int i = 0; i < 8; ++i)
        acc[i][0] = acc[i][1] = acc[i][2] = acc[i][3] = 0.f;

    for (int k = 0; k < 128; k += 4) {
        float4 w0 = *(const float4*)&sW[(k + 0) * 128 + c0];
        float4 w1 = *(const float4*)&sW[(k + 1) * 128 + c0];
        float4 w2 = *(const float4*)&sW[(k + 2) * 128 + c0];
        float4 w3 = *(const float4*)&sW[(k + 3) * 128 + c0];
#pragma unroll
        for (int i = 0; i < 8; ++i) {
            float4 xv = *(const float4*)&sX[(n0 + i) * 128 + k];
            acc[i][0] = fmaf(xv.x, w0.x, acc[i][0]); acc[i][1] = fmaf(xv.x, w0.y, acc[i][1]);
            acc[i][2] = fmaf(xv.x, w0.z, acc[i][2]); acc[i][3] = fmaf(xv.x, w0.w, acc[i][3]);
            acc[i][0] = fmaf(xv.y, w1.x, acc[i][0]); acc[i][1] = fmaf(xv.y, w1.y, acc[i][1]);
            acc[i][2] = fmaf(xv.y, w1.z, acc[i][2]); acc[i][3] = fmaf(xv.y, w1.w, acc[i][3]);
            acc[i][0] = fmaf(xv.z, w2.x, acc[i][0]); acc[i][1] = fmaf(xv.z, w2.y, acc[i][1]);
            acc[i][2] = fmaf(xv.z, w2.z, acc[i][2]); acc[i][3] = fmaf(xv.z, w2.w, acc[i][3]);
            acc[i][0] = fmaf(xv.w, w3.x, acc[i][0]); acc[i][1] = fmaf(xv.w, w3.y, acc[i][1]);
            acc[i][2] = fmaf(xv.w, w3.z, acc[i][2]); acc[i][3] = fmaf(xv.w, w3.w, acc[i][3]);
        }
    }
#pragma unroll
    for (int i = 0; i < 8; ++i) {
        int n = n0 + i;
        if (n < nrows) {
            float4 st = make_float4(acc[i][0], acc[i][1], acc[i][2], acc[i][3]);
            *(float4*)&h1[((size_t)(nbase + n)) * 128 + c0] = st;
        }
    }
}

// -------- per-node attention logits layer 1 --------
__global__ void k_alphas1(const float* __restrict__ h1, const float* __restrict__ a_s,
                          const float* __restrict__ a_d,
                          float* __restrict__ as1, float* __restrict__ ad1) {
    int t = blockIdx.x * 256 + threadIdx.x;
    if (t >= NNODES * 4) return;
    int n = t >> 2, h = t & 3;
    const float4* hp = (const float4*)(h1 + (size_t)n * 128 + h * 32);
    const float4* sp = (const float4*)(a_s + h * 32);
    const float4* dp = (const float4*)(a_d + h * 32);
    float ss = 0.f, sd = 0.f;
#pragma unroll
    for (int i = 0; i < 8; ++i) {
        float4 hv = hp[i], av = sp[i], bv = dp[i];
        ss += hv.x * av.x + hv.y * av.y + hv.z * av.z + hv.w * av.w;
        sd += hv.x * bv.x + hv.y * bv.y + hv.z * bv.z + hv.w * bv.w;
    }
    as1[t] = ss; ad1[t] = sd;
}

// -------- layer-1 aggregation: 32 lanes per node, atomic-free --------
__global__ __launch_bounds__(256) void k_node1(const int* __restrict__ csr_src,
        const int* __restrict__ excl, const int* __restrict__ bsum,
        const int* __restrict__ cnt, const float* __restrict__ h1,
        const float* __restrict__ as1, const float* __restrict__ ad1,
        float* __restrict__ out1) {
    int t = threadIdx.x;
    int node = blockIdx.x * 8 + (t >> 5);
    if (node >= NNODES) return;
    int lane = t & 31, head = lane >> 3;
    int off = excl[node] + bsum[node >> 10];
    int deg = cnt[node];
    float ad_h = ad1[node * 4 + head];

    float denom = 0.f;
    for (int base = 0; base < deg; base += 32) {
        int m = deg - base; if (m > 32) m = 32;
        int sv = (lane < m) ? csr_src[off + base + lane] : 0;
        for (int i = 0; i < m; ++i) {
            int s = __shfl(sv, i, 32);
            float v = as1[s * 4 + head] + ad_h;
            v = v > 0.f ? v : NEG * v;
            denom += __expf(v);
        }
    }
    float inv = 1.f / denom;   // deg >= 1 (self-loop) -> denom > 0

    float4 acc = make_float4(0.f, 0.f, 0.f, 0.f);
    for (int base = 0; base < deg; base += 32) {
        int m = deg - base; if (m > 32) m = 32;
        int sv = (lane < m) ? csr_src[off + base + lane] : 0;
        for (int i = 0; i < m; ++i) {
            int s = __shfl(sv, i, 32);
            float v = as1[s * 4 + head] + ad_h;
            v = v > 0.f ? v : NEG * v;
            float alpha = __expf(v) * inv;
            float4 hv = *(const float4*)(h1 + (size_t)s * 128 + lane * 4);
            acc.x = fmaf(hv.x, alpha, acc.x);
            acc.y = fmaf(hv.y, alpha, acc.y);
            acc.z = fmaf(hv.z, alpha, acc.z);
            acc.w = fmaf(hv.w, alpha, acc.w);
        }
    }
    *(float4*)(out1 + (size_t)node * 128 + lane * 4) = acc;
}

// ---- GEMM2: h2[N,40] = ELU(out1 + b1) @ W2[128,40] ----
__global__ __launch_bounds__(256) void k_gemm2(const float* __restrict__ in,
                                               const float* __restrict__ W2,
                                               const float* __restrict__ b1,
                                               float* __restrict__ h2) {
    __shared__ float sW[128 * 40];    // 20 KB
    __shared__ float sX[128 * 132];   // padded rows
    int t = threadIdx.x;
    for (int i = t; i < 128 * 40 / 4; i += 256) ((float4*)sW)[i] = ((const float4*)W2)[i];
    int nbase = blockIdx.x * 128;
    int nrows = NNODES - nbase; if (nrows > 128) nrows = 128;
    {
        const float4* X4 = (const float4*)(in + (size_t)nbase * 128);
        for (int i = t; i < nrows * 32; i += 256) {
            int row = i >> 5, c4 = i & 31;
            float4 v = X4[i];
            float4 bb = *(const float4*)&b1[c4 * 4];
            v.x += bb.x; v.y += bb.y; v.z += bb.z; v.w += bb.w;
            v.x = v.x > 0.f ? v.x : __expf(v.x) - 1.f;
            v.y = v.y > 0.f ? v.y : __expf(v.y) - 1.f;
            v.z = v.z > 0.f ? v.z : __expf(v.z) - 1.f;
            v.w = v.w > 0.f ? v.w : __expf(v.w) - 1.f;
            *(float4*)&sX[row * 132 + c4 * 4] = v;
        }
    }
    __syncthreads();

    int colg = t & 7, nodeg = t >> 3;
    int c0 = colg * 5;
    float acc[4][5];
#pragma unroll
    for (int i = 0; i < 4; ++i)
#pragma unroll
        for (int c = 0; c < 5; ++c) acc[i][c] = 0.f;

    for (int k = 0; k < 128; k += 4) {
        float4 xv[4];
#pragma unroll
        for (int i = 0; i < 4; ++i)
            xv[i] = *(const float4*)&sX[(nodeg + 32 * i) * 132 + k];
#pragma unroll
        for (int j = 0; j < 4; ++j) {
            float w0 = sW[(k + j) * 40 + c0 + 0];
            float w1 = sW[(k + j) * 40 + c0 + 1];
            float w2 = sW[(k + j) * 40 + c0 + 2];
            float w3 = sW[(k + j) * 40 + c0 + 3];
            float w4 = sW[(k + j) * 40 + c0 + 4];
#pragma unroll
            for (int i = 0; i < 4; ++i) {
                float xs = f4get(xv[i], j);
                acc[i][0] = fmaf(xs, w0, acc[i][0]);
                acc[i][1] = fmaf(xs, w1, acc[i][1]);
                acc[i][2] = fmaf(xs, w2, acc[i][2]);
                acc[i][3] = fmaf(xs, w3, acc[i][3]);
                acc[i][4] = fmaf(xs, w4, acc[i][4]);
            }
        }
    }
#pragma unroll
    for (int i = 0; i < 4; ++i) {
        int n = nodeg + 32 * i;
        if (n < nrows) {
            float* op = h2 + (size_t)(nbase + n) * 40 + c0;
#pragma unroll
            for (int c = 0; c < 5; ++c) op[c] = acc[i][c];
        }
    }
}

// -------- per-node attention logits layer 2 --------
__global__ void k_alphas2(const float* __restrict__ h2, const float* __restrict__ a_s,
                          const float* __restrict__ a_d,
                          float* __restrict__ as2, float* __restrict__ ad2) {
    int n = blockIdx.x * 256 + threadIdx.x;
    if (n >= NNODES) return;
    const float4* hp = (const float4*)(h2 + (size_t)n * 40);
    float ss = 0.f, sd = 0.f;
#pragma unroll
    for (int i = 0; i < 10; ++i) {
        float4 hv = hp[i];
        float4 av = ((const float4*)a_s)[i];
        float4 bv = ((const float4*)a_d)[i];
        ss += hv.x * av.x + hv.y * av.y + hv.z * av.z + hv.w * av.w;
        sd += hv.x * bv.x + hv.y * bv.y + hv.z * bv.z + hv.w * bv.w;
    }
    as2[n] = ss; ad2[n] = sd;
}

// -------- layer-2 aggregation: 10 lanes per node (40 ch = 10 float4) --------
__global__ __launch_bounds__(320) void k_node2(const int* __restrict__ csr_src,
        const int* __restrict__ excl, const int* __restrict__ bsum,
        const int* __restrict__ cnt, const float* __restrict__ h2,
        const float* __restrict__ as2, const float* __restrict__ ad2,
        float* __restrict__ out2) {
    unsigned t = blockIdx.x * 320u + threadIdx.x;
    unsigned node = t / 10u;
    if (node >= NNODES) return;
    int q = (int)(t - node * 10u);
    int off = excl[node] + bsum[node >> 10];
    int deg = cnt[node];
    float ad_v = ad2[node];

    float denom = 0.f;
    for (int i = 0; i < deg; ++i) {
        int s = csr_src[off + i];
        float v = as2[s] + ad_v;
        v = v > 0.f ? v : NEG * v;
        denom += __expf(v);
    }
    float inv = 1.f / denom;

    float4 acc = make_float4(0.f, 0.f, 0.f, 0.f);
    for (int i = 0; i < deg; ++i) {
        int s = csr_src[off + i];
        float v = as2[s] + ad_v;
        v = v > 0.f ? v : NEG * v;
        float alpha = __expf(v) * inv;
        float4 hv = *(const float4*)(h2 + (size_t)s * 40 + q * 4);
        acc.x = fmaf(hv.x, alpha, acc.x);
        acc.y = fmaf(hv.y, alpha, acc.y);
        acc.z = fmaf(hv.z, alpha, acc.z);
        acc.w = fmaf(hv.w, alpha, acc.w);
    }
    *(float4*)(out2 + (size_t)node * 40 + q * 4) = acc;
}

// -------- global mean pool --------
__global__ __launch_bounds__(256) void k_pool(const float* __restrict__ out2,
        const int* __restrict__ batch, const float* __restrict__ b2,
        float* __restrict__ out) {
    int g = blockIdx.x;
    int lo, hi;
    { int a = 0, b = NNODES; while (a < b) { int m = (a + b) >> 1; if (batch[m] < g) a = m + 1; else b = m; } lo = a; }
    { int a = lo, b = NNODES; while (a < b) { int m = (a + b) >> 1; if (batch[m] < g + 1) a = m + 1; else b = m; } hi = a; }
    int cnt = hi - lo;
    int t = threadIdx.x;
    float sum = 0.f;
    if (t < 240) {
        int c = t % 40, r = t / 40;
        for (int n = lo + r; n < hi; n += 6) sum += out2[(size_t)n * 40 + c];
    }
    __shared__ float red[240];
    if (t < 240) red[t] = sum;
    __syncthreads();
    if (t < 40) {
        float s2 = red[t] + red[t + 40] + red[t + 80] + red[t + 120] + red[t + 160] + red[t + 200];
        out[g * 40 + t] = cnt > 0 ? (s2 / (float)cnt + b2[t]) : 0.f;
    }
}

extern "C" void kernel_launch(void* const* d_in, const int* in_sizes, int n_in,
                              void* d_out, int out_size, void* d_ws, size_t ws_size,
                              hipStream_t stream) {
    const float* x    = (const float*)d_in[0];
    const int*   ei   = (const int*)d_in[1];
    const int*   batch= (const int*)d_in[2];
    const float* W1   = (const float*)d_in[3];
    const float* a1s  = (const float*)d_in[4];
    const float* a1d  = (const float*)d_in[5];
    const float* b1   = (const float*)d_in[6];
    const float* W2   = (const float*)d_in[7];
    const float* a2s  = (const float*)d_in[8];
    const float* a2d  = (const float*)d_in[9];
    const float* b2   = (const float*)d_in[10];
    float* out = (float*)d_out;

    // ---- workspace layout ----
    int* cnt    = (int*)d_ws;               // N      (memset 0)
    int* cursor = cnt + NNODES;             // N      (memset 0)
    int* excl   = cursor + NNODES;          // N
    int* boffs  = excl + NNODES;            // 128
    int* csr    = boffs + 128;              // ETOT
    float* h1   = (float*)(csr + ETOT);     // N*128  (16B-aligned: offset 8000512 B)
    float* as1  = h1 + (size_t)NNODES * 128;   // N*4
    float* ad1  = as1 + (size_t)NNODES * 4;    // N*4
    float* out1 = ad1 + (size_t)NNODES * 4;    // N*128
    float* as2  = out1 + (size_t)NNODES * 128; // N
    float* ad2  = as2 + NNODES;                // N
    // aliases into h1 region (h1 dead after k_node1; gemm2 reads out1 only)
    float* h2   = h1;                          // N*40
    float* out2 = h1 + (size_t)NNODES * 40;    // N*40  (disjoint from h2)

    hipMemsetAsync(d_ws, 0, (size_t)2 * NNODES * sizeof(int), stream);

    // CSR build
    k_hist<<<(ETOT + 255) / 256, 256, 0, stream>>>(ei, cnt);
    k_scan1<<<NB_SCAN, 256, 0, stream>>>(cnt, excl, boffs);
    k_scan2<<<1, 64, 0, stream>>>(boffs);
    k_scatter<<<(ETOT + 255) / 256, 256, 0, stream>>>(ei, excl, boffs, cursor, csr);

    // layer 1
    k_gemm1<<<(NNODES + 63) / 64, 256, 0, stream>>>(x, W1, h1);
    k_alphas1<<<(NNODES * 4 + 255) / 256, 256, 0, stream>>>(h1, a1s, a1d, as1, ad1);
    k_node1<<<(NNODES + 7) / 8, 256, 0, stream>>>(csr, excl, boffs, cnt, h1, as1, ad1, out1);

    // layer 2
    k_gemm2<<<(NNODES + 127) / 128, 256, 0, stream>>>(out1, W2, b1, h2);
    k_alphas2<<<(NNODES + 255) / 256, 256, 0, stream>>>(h2, a2s, a2d, as2, ad2);
    k_node2<<<(NNODES * 10 + 319) / 320, 320, 0, stream>>>(csr, excl, boffs, cnt, h2, as2, ad2, out2);

    // pool
    k_pool<<<NGRAPH, 256, 0, stream>>>(out2, batch, b2, out);
}

// Round 4
// 535.940 us; speedup vs baseline: 8.4929x; 1.2586x over previous
//
#include <hip/hip_runtime.h>

#define NNODES 100000
#define NEDGES 1600000
#define ETOT   1700000   // NEDGES + NNODES self-loops
#define NGRAPH 64
#define NEG    0.2f
#define NB_SCAN 98       // ceil(NNODES / 1024)

__device__ __forceinline__ float f4get(const float4& v, int j) {
    return j == 0 ? v.x : j == 1 ? v.y : j == 2 ? v.z : v.w;
}

__device__ __forceinline__ unsigned short f2bf(float f) {   // RNE f32->bf16
    unsigned u = __float_as_uint(f);
    u = (u + 0x7fffu + ((u >> 16) & 1u)) >> 16;
    return (unsigned short)u;
}
__device__ __forceinline__ float bf_lo(unsigned u) { return __uint_as_float(u << 16); }
__device__ __forceinline__ float bf_hi(unsigned u) { return __uint_as_float(u & 0xffff0000u); }

__device__ __forceinline__ void edge_sd(const int* __restrict__ ei, int e, int& s, int& d) {
    if (e < NEDGES) { s = ei[e]; d = ei[NEDGES + e]; }
    else            { s = d = e - NEDGES; }
}

// ======================= CSR build =======================
__global__ void k_hist(const int* __restrict__ ei, int* __restrict__ cnt) {
    int e = blockIdx.x * 256 + threadIdx.x;
    if (e >= ETOT) return;
    int s, d; edge_sd(ei, e, s, d);
    atomicAdd(&cnt[d], 1);
}

__global__ __launch_bounds__(256) void k_scan1(const int* __restrict__ cnt,
                                               int* __restrict__ excl,
                                               int* __restrict__ bsum) {
    __shared__ int tmp[256];
    int t = threadIdx.x;
    int base = blockIdx.x * 1024 + t * 4;
    int v0 = base + 0 < NNODES ? cnt[base + 0] : 0;
    int v1 = base + 1 < NNODES ? cnt[base + 1] : 0;
    int v2 = base + 2 < NNODES ? cnt[base + 2] : 0;
    int v3 = base + 3 < NNODES ? cnt[base + 3] : 0;
    int tot = v0 + v1 + v2 + v3;
    tmp[t] = tot;
    __syncthreads();
    for (int off = 1; off < 256; off <<= 1) {
        int x = (t >= off) ? tmp[t - off] : 0;
        __syncthreads();
        tmp[t] += x;
        __syncthreads();
    }
    int tbase = tmp[t] - tot;
    if (base + 0 < NNODES) excl[base + 0] = tbase;
    if (base + 1 < NNODES) excl[base + 1] = tbase + v0;
    if (base + 2 < NNODES) excl[base + 2] = tbase + v0 + v1;
    if (base + 3 < NNODES) excl[base + 3] = tbase + v0 + v1 + v2;
    if (t == 255) bsum[blockIdx.x] = tmp[255];
}

__global__ void k_scan2(int* __restrict__ bsum) {
    if (threadIdx.x == 0 && blockIdx.x == 0) {
        int acc = 0;
        for (int i = 0; i < NB_SCAN; ++i) { int v = bsum[i]; bsum[i] = acc; acc += v; }
    }
}

__global__ void k_scatter(const int* __restrict__ ei, const int* __restrict__ excl,
                          const int* __restrict__ bsum, int* __restrict__ cursor,
                          int* __restrict__ csr_src) {
    int e = blockIdx.x * 256 + threadIdx.x;
    if (e >= ETOT) return;
    int s, d; edge_sd(ei, e, s, d);
    int pos = excl[d] + bsum[d >> 10] + atomicAdd(&cursor[d], 1);
    csr_src[pos] = s;
}

// ---------------- GEMM1 + fused alphas + bf16 store ----------------
// h1b[N,128] (bf16) = x @ W1 ; as1/ad1[N,4] = h1 . a1_{src,dst}
__global__ __launch_bounds__(256) void k_gemm1(const float* __restrict__ x,
                                               const float* __restrict__ W1,
                                               const float* __restrict__ a1s,
                                               const float* __restrict__ a1d,
                                               unsigned short* __restrict__ h1b,
                                               float* __restrict__ as1,
                                               float* __restrict__ ad1) {
    __shared__ float sW[128 * 128];   // 64 KB
    __shared__ float sX[64 * 128];    // 32 KB
    int t = threadIdx.x;
    {
        const float4* W4 = (const float4*)W1;
        float4* sW4 = (float4*)sW;
#pragma unroll
        for (int i = 0; i < 16; ++i) sW4[t + 256 * i] = W4[t + 256 * i];
    }
    int nbase = blockIdx.x * 64;
    int nrows = NNODES - nbase; if (nrows > 64) nrows = 64;
    {
        const float4* X4 = (const float4*)(x + (size_t)nbase * 128);
        float4* sX4 = (float4*)sX;
        for (int i = t; i < nrows * 32; i += 256) sX4[i] = X4[i];
    }
    __syncthreads();

    int colg = t & 31, rowg = t >> 5;
    int c0 = colg * 4, n0 = rowg * 8;
    float acc[8][4];
#pragma unroll
    for (int i = 0; i < 8; ++i)
        acc[i][0] = acc[i][1] = acc[i][2] = acc[i][3] = 0.f;

    for (int k = 0; k < 128; k += 4) {
        float4 w0 = *(const float4*)&sW[(k + 0) * 128 + c0];
        float4 w1 = *(const float4*)&sW[(k + 1) * 128 + c0];
        float4 w2 = *(const float4*)&sW[(k + 2) * 128 + c0];
        float4 w3 = *(const float4*)&sW[(k + 3) * 128 + c0];
#pragma unroll
        for (int i = 0; i < 8; ++i) {
            float4 xv = *(const float4*)&sX[(n0 + i) * 128 + k];
            acc[i][0] = fmaf(xv.x, w0.x, acc[i][0]); acc[i][1] = fmaf(xv.x, w0.y, acc[i][1]);
            acc[i][2] = fmaf(xv.x, w0.z, acc[i][2]); acc[i][3] = fmaf(xv.x, w0.w, acc[i][3]);
            acc[i][0] = fmaf(xv.y, w1.x, acc[i][0]); acc[i][1] = fmaf(xv.y, w1.y, acc[i][1]);
            acc[i][2] = fmaf(xv.y, w1.z, acc[i][2]); acc[i][3] = fmaf(xv.y, w1.w, acc[i][3]);
            acc[i][0] = fmaf(xv.z, w2.x, acc[i][0]); acc[i][1] = fmaf(xv.z, w2.y, acc[i][1]);
            acc[i][2] = fmaf(xv.z, w2.z, acc[i][2]); acc[i][3] = fmaf(xv.z, w2.w, acc[i][3]);
            acc[i][0] = fmaf(xv.w, w3.x, acc[i][0]); acc[i][1] = fmaf(xv.w, w3.y, acc[i][1]);
            acc[i][2] = fmaf(xv.w, w3.z, acc[i][2]); acc[i][3] = fmaf(xv.w, w3.w, acc[i][3]);
        }
    }

    // epilogue: bf16 store + fused attention logits
    int head = colg >> 3;
    float ws0 = a1s[c0], ws1 = a1s[c0 + 1], ws2 = a1s[c0 + 2], ws3 = a1s[c0 + 3];
    float wd0 = a1d[c0], wd1 = a1d[c0 + 1], wd2 = a1d[c0 + 2], wd3 = a1d[c0 + 3];
#pragma unroll
    for (int i = 0; i < 8; ++i) {
        int n = n0 + i;
        // partial dots over this thread's 4 channels
        float ps = acc[i][0] * ws0 + acc[i][1] * ws1 + acc[i][2] * ws2 + acc[i][3] * ws3;
        float pd = acc[i][0] * wd0 + acc[i][1] * wd1 + acc[i][2] * wd2 + acc[i][3] * wd3;
        // reduce over the 8 column-groups of this head (lanes xor 1,2,4)
        ps += __shfl_xor(ps, 1); ps += __shfl_xor(ps, 2); ps += __shfl_xor(ps, 4);
        pd += __shfl_xor(pd, 1); pd += __shfl_xor(pd, 2); pd += __shfl_xor(pd, 4);
        if (n < nrows) {
            unsigned b0 = f2bf(acc[i][0]), b1 = f2bf(acc[i][1]);
            unsigned b2 = f2bf(acc[i][2]), b3 = f2bf(acc[i][3]);
            uint2 pk; pk.x = b0 | (b1 << 16); pk.y = b2 | (b3 << 16);
            *(uint2*)&h1b[((size_t)(nbase + n)) * 128 + c0] = pk;
            if ((colg & 7) == 0) {
                as1[(size_t)(nbase + n) * 4 + head] = ps;
                ad1[(size_t)(nbase + n) * 4 + head] = pd;
            }
        }
    }
}

// -------- layer-1 aggregation: 32 lanes/node, single pass, postponed division --------
__global__ __launch_bounds__(256) void k_node1(const int* __restrict__ csr_src,
        const int* __restrict__ excl, const int* __restrict__ bsum,
        const int* __restrict__ cnt, const unsigned short* __restrict__ h1b,
        const float4* __restrict__ as1v, const float4* __restrict__ ad1v,
        float* __restrict__ out1) {
    __shared__ float4 exbuf[8][32];
    int t = threadIdx.x;
    int grp = t >> 5, lane = t & 31;
    int node = blockIdx.x * 8 + grp;
    if (node >= NNODES) return;
    int head = lane >> 3;
    int off = excl[node] + bsum[node >> 10];
    int deg = cnt[node];
    float4 adv = ad1v[node];
    float4 dp = make_float4(0.f, 0.f, 0.f, 0.f);
    float4 acc = make_float4(0.f, 0.f, 0.f, 0.f);
    const float* exs = (const float*)&exbuf[grp][0];

    for (int base = 0; base < deg; base += 32) {
        int m = deg - base; if (m > 32) m = 32;
        int sv = 0;
        if (lane < m) {
            sv = csr_src[off + base + lane];
            float4 av = as1v[sv];
            float v; float4 e;
            v = av.x + adv.x; v = v > 0.f ? v : NEG * v; e.x = __expf(v);
            v = av.y + adv.y; v = v > 0.f ? v : NEG * v; e.y = __expf(v);
            v = av.z + adv.z; v = v > 0.f ? v : NEG * v; e.z = __expf(v);
            v = av.w + adv.w; v = v > 0.f ? v : NEG * v; e.w = __expf(v);
            exbuf[grp][lane] = e;
            dp.x += e.x; dp.y += e.y; dp.z += e.z; dp.w += e.w;
        }
        __builtin_amdgcn_wave_barrier();   // keep ds_write before the reads below
        for (int i = 0; i < m; ++i) {
            int s = __shfl(sv, i, 32);
            float a = exs[i * 4 + head];
            uint2 hv = *(const uint2*)(h1b + (size_t)s * 128 + lane * 4);
            acc.x = fmaf(bf_lo(hv.x), a, acc.x);
            acc.y = fmaf(bf_hi(hv.x), a, acc.y);
            acc.z = fmaf(bf_lo(hv.y), a, acc.z);
            acc.w = fmaf(bf_hi(hv.y), a, acc.w);
        }
        __builtin_amdgcn_wave_barrier();   // reads done before next chunk's write
    }
    // butterfly-reduce denom over the 32-lane group
#pragma unroll
    for (int msk = 1; msk < 32; msk <<= 1) {
        dp.x += __shfl_xor(dp.x, msk, 32);
        dp.y += __shfl_xor(dp.y, msk, 32);
        dp.z += __shfl_xor(dp.z, msk, 32);
        dp.w += __shfl_xor(dp.w, msk, 32);
    }
    float inv = 1.f / f4get(dp, head);
    float4 o; o.x = acc.x * inv; o.y = acc.y * inv; o.z = acc.z * inv; o.w = acc.w * inv;
    *(float4*)(out1 + (size_t)node * 128 + lane * 4) = o;
}

// ---- GEMM2 + fused alphas2 + bf16 store: h2b[N,40] = ELU(out1+b1) @ W2 ----
__global__ __launch_bounds__(256) void k_gemm2(const float* __restrict__ in,
                                               const float* __restrict__ W2,
                                               const float* __restrict__ b1,
                                               const float* __restrict__ a2s,
                                               const float* __restrict__ a2d,
                                               unsigned short* __restrict__ h2b,
                                               float* __restrict__ as2,
                                               float* __restrict__ ad2) {
    __shared__ float sW[128 * 40];
    __shared__ float sX[128 * 132];
    int t = threadIdx.x;
    for (int i = t; i < 128 * 40 / 4; i += 256) ((float4*)sW)[i] = ((const float4*)W2)[i];
    int nbase = blockIdx.x * 128;
    int nrows = NNODES - nbase; if (nrows > 128) nrows = 128;
    {
        const float4* X4 = (const float4*)(in + (size_t)nbase * 128);
        for (int i = t; i < nrows * 32; i += 256) {
            int row = i >> 5, c4 = i & 31;
            float4 v = X4[i];
            float4 bb = *(const float4*)&b1[c4 * 4];
            v.x += bb.x; v.y += bb.y; v.z += bb.z; v.w += bb.w;
            v.x = v.x > 0.f ? v.x : __expf(v.x) - 1.f;
            v.y = v.y > 0.f ? v.y : __expf(v.y) - 1.f;
            v.z = v.z > 0.f ? v.z : __expf(v.z) - 1.f;
            v.w = v.w > 0.f ? v.w : __expf(v.w) - 1.f;
            *(float4*)&sX[row * 132 + c4 * 4] = v;
        }
    }
    __syncthreads();

    int colg = t & 7, nodeg = t >> 3;
    int c0 = colg * 5;
    float acc[4][5];
#pragma unroll
    for (int i = 0; i < 4; ++i)
#pragma unroll
        for (int c = 0; c < 5; ++c) acc[i][c] = 0.f;

    for (int k = 0; k < 128; k += 4) {
        float4 xv[4];
#pragma unroll
        for (int i = 0; i < 4; ++i)
            xv[i] = *(const float4*)&sX[(nodeg + 32 * i) * 132 + k];
#pragma unroll
        for (int j = 0; j < 4; ++j) {
            float w0 = sW[(k + j) * 40 + c0 + 0];
            float w1 = sW[(k + j) * 40 + c0 + 1];
            float w2 = sW[(k + j) * 40 + c0 + 2];
            float w3 = sW[(k + j) * 40 + c0 + 3];
            float w4 = sW[(k + j) * 40 + c0 + 4];
#pragma unroll
            for (int i = 0; i < 4; ++i) {
                float xs = f4get(xv[i], j);
                acc[i][0] = fmaf(xs, w0, acc[i][0]);
                acc[i][1] = fmaf(xs, w1, acc[i][1]);
                acc[i][2] = fmaf(xs, w2, acc[i][2]);
                acc[i][3] = fmaf(xs, w3, acc[i][3]);
                acc[i][4] = fmaf(xs, w4, acc[i][4]);
            }
        }
    }

    float ws0 = a2s[c0], ws1 = a2s[c0 + 1], ws2 = a2s[c0 + 2], ws3 = a2s[c0 + 3], ws4 = a2s[c0 + 4];
    float wd0 = a2d[c0], wd1 = a2d[c0 + 1], wd2 = a2d[c0 + 2], wd3 = a2d[c0 + 3], wd4 = a2d[c0 + 4];
#pragma unroll
    for (int i = 0; i < 4; ++i) {
        int n = nodeg + 32 * i;
        float ps = acc[i][0]*ws0 + acc[i][1]*ws1 + acc[i][2]*ws2 + acc[i][3]*ws3 + acc[i][4]*ws4;
        float pd = acc[i][0]*wd0 + acc[i][1]*wd1 + acc[i][2]*wd2 + acc[i][3]*wd3 + acc[i][4]*wd4;
        ps += __shfl_xor(ps, 1); ps += __shfl_xor(ps, 2); ps += __shfl_xor(ps, 4);
        pd += __shfl_xor(pd, 1); pd += __shfl_xor(pd, 2); pd += __shfl_xor(pd, 4);
        if (n < nrows) {
            unsigned short* hp = h2b + (size_t)(nbase + n) * 40 + c0;
#pragma unroll
            for (int c = 0; c < 5; ++c) hp[c] = f2bf(acc[i][c]);
            if (colg == 0) {
                as2[nbase + n] = ps;
                ad2[nbase + n] = pd;
            }
        }
    }
}

// -------- layer-2 aggregation: 16 lanes/node (lanes 0..9 carry channels) --------
__global__ __launch_bounds__(256) void k_node2(const int* __restrict__ csr_src,
        const int* __restrict__ excl, const int* __restrict__ bsum,
        const int* __restrict__ cnt, const unsigned short* __restrict__ h2b,
        const float* __restrict__ as2, const float* __restrict__ ad2,
        float* __restrict__ out2) {
    int t = threadIdx.x;
    int grp = t >> 4, lane = t & 15;
    int node = blockIdx.x * 16 + grp;
    if (node >= NNODES) return;
    int off = excl[node] + bsum[node >> 10];
    int deg = cnt[node];
    float adv = ad2[node];
    float dp = 0.f;
    float4 acc = make_float4(0.f, 0.f, 0.f, 0.f);

    for (int base = 0; base < deg; base += 16) {
        int m = deg - base; if (m > 16) m = 16;
        int sv = 0; float ex = 0.f;
        if (lane < m) {
            sv = csr_src[off + base + lane];
            float v = as2[sv] + adv;
            v = v > 0.f ? v : NEG * v;
            ex = __expf(v);
            dp += ex;
        }
        for (int i = 0; i < m; ++i) {
            int s = __shfl(sv, i, 16);
            float a = __shfl(ex, i, 16);
            if (lane < 10) {
                uint2 hv = *(const uint2*)(h2b + (size_t)s * 40 + lane * 4);
                acc.x = fmaf(bf_lo(hv.x), a, acc.x);
                acc.y = fmaf(bf_hi(hv.x), a, acc.y);
                acc.z = fmaf(bf_lo(hv.y), a, acc.z);
                acc.w = fmaf(bf_hi(hv.y), a, acc.w);
            }
        }
    }
#pragma unroll
    for (int msk = 1; msk < 16; msk <<= 1) dp += __shfl_xor(dp, msk, 16);
    float inv = 1.f / dp;
    if (lane < 10) {
        float4 o; o.x = acc.x * inv; o.y = acc.y * inv; o.z = acc.z * inv; o.w = acc.w * inv;
        *(float4*)(out2 + (size_t)node * 40 + lane * 4) = o;
    }
}

// -------- global mean pool --------
__global__ __launch_bounds__(256) void k_pool(const float* __restrict__ out2,
        const int* __restrict__ batch, const float* __restrict__ b2,
        float* __restrict__ out) {
    int g = blockIdx.x;
    int lo, hi;
    { int a = 0, b = NNODES; while (a < b) { int m = (a + b) >> 1; if (batch[m] < g) a = m + 1; else b = m; } lo = a; }
    { int a = lo, b = NNODES; while (a < b) { int m = (a + b) >> 1; if (batch[m] < g + 1) a = m + 1; else b = m; } hi = a; }
    int cnt = hi - lo;
    int t = threadIdx.x;
    float sum = 0.f;
    if (t < 240) {
        int c = t % 40, r = t / 40;
        for (int n = lo + r; n < hi; n += 6) sum += out2[(size_t)n * 40 + c];
    }
    __shared__ float red[240];
    if (t < 240) red[t] = sum;
    __syncthreads();
    if (t < 40) {
        float s2 = red[t] + red[t + 40] + red[t + 80] + red[t + 120] + red[t + 160] + red[t + 200];
        out[g * 40 + t] = cnt > 0 ? (s2 / (float)cnt + b2[t]) : 0.f;
    }
}

extern "C" void kernel_launch(void* const* d_in, const int* in_sizes, int n_in,
                              void* d_out, int out_size, void* d_ws, size_t ws_size,
                              hipStream_t stream) {
    const float* x    = (const float*)d_in[0];
    const int*   ei   = (const int*)d_in[1];
    const int*   batch= (const int*)d_in[2];
    const float* W1   = (const float*)d_in[3];
    const float* a1s  = (const float*)d_in[4];
    const float* a1d  = (const float*)d_in[5];
    const float* b1   = (const float*)d_in[6];
    const float* W2   = (const float*)d_in[7];
    const float* a2s  = (const float*)d_in[8];
    const float* a2d  = (const float*)d_in[9];
    const float* b2   = (const float*)d_in[10];
    float* out = (float*)d_out;

    // ---- workspace layout (all segment sizes multiples of 16 B) ----
    int* cnt    = (int*)d_ws;                       // N   (memset 0)
    int* cursor = cnt + NNODES;                     // N   (memset 0)
    int* excl   = cursor + NNODES;                  // N
    int* boffs  = excl + NNODES;                    // 128
    int* csr    = boffs + 128;                      // ETOT
    float* as1  = (float*)(csr + ETOT);             // N*4
    float* ad1  = as1 + (size_t)NNODES * 4;         // N*4
    unsigned short* h1b = (unsigned short*)(ad1 + (size_t)NNODES * 4);  // N*128 bf16
    float* out1 = (float*)(h1b + (size_t)NNODES * 128);                 // N*128 f32
    float* as2  = out1 + (size_t)NNODES * 128;      // N
    float* ad2  = as2 + NNODES;                     // N
    unsigned short* h2b = (unsigned short*)(ad2 + NNODES);              // N*40 bf16
    float* out2 = (float*)(h2b + (size_t)NNODES * 40);                  // N*40 f32

    hipMemsetAsync(d_ws, 0, (size_t)2 * NNODES * sizeof(int), stream);

    // CSR build
    k_hist<<<(ETOT + 255) / 256, 256, 0, stream>>>(ei, cnt);
    k_scan1<<<NB_SCAN, 256, 0, stream>>>(cnt, excl, boffs);
    k_scan2<<<1, 64, 0, stream>>>(boffs);
    k_scatter<<<(ETOT + 255) / 256, 256, 0, stream>>>(ei, excl, boffs, cursor, csr);

    // layer 1
    k_gemm1<<<(NNODES + 63) / 64, 256, 0, stream>>>(x, W1, a1s, a1d, h1b, as1, ad1);
    k_node1<<<(NNODES + 7) / 8, 256, 0, stream>>>(csr, excl, boffs, cnt, h1b,
                                                  (const float4*)as1, (const float4*)ad1, out1);

    // layer 2
    k_gemm2<<<(NNODES + 127) / 128, 256, 0, stream>>>(out1, W2, b1, a2s, a2d, h2b, as2, ad2);
    k_node2<<<(NNODES + 15) / 16, 256, 0, stream>>>(csr, excl, boffs, cnt, h2b, as2, ad2, out2);

    // pool
    k_pool<<<NGRAPH, 256, 0, stream>>>(out2, batch, b2, out);
}

// Round 5
// 481.446 us; speedup vs baseline: 9.4542x; 1.1132x over previous
//
#include <hip/hip_runtime.h>

#define NNODES 100000
#define NEDGES 1600000
#define ETOT   1700000   // NEDGES + NNODES self-loops
#define NGRAPH 64
#define NEG    0.2f
#define NB_SCAN 98       // ceil(NNODES / 1024)
#define NPART  8
#define PSZ    ((ETOT + NPART - 1) / NPART)   // 212500 csr slots per partition
#define SCAT_BPP 128                          // blocks per partition
#define SCAT_CH  ((ETOT + SCAT_BPP - 1) / SCAT_BPP)  // 13282 edges per chunk

__device__ __forceinline__ float f4get(const float4& v, int j) {
    return j == 0 ? v.x : j == 1 ? v.y : j == 2 ? v.z : v.w;
}

__device__ __forceinline__ unsigned short f2bf(float f) {   // RNE f32->bf16
    unsigned u = __float_as_uint(f);
    u = (u + 0x7fffu + ((u >> 16) & 1u)) >> 16;
    return (unsigned short)u;
}
__device__ __forceinline__ float bf_lo(unsigned u) { return __uint_as_float(u << 16); }
__device__ __forceinline__ float bf_hi(unsigned u) { return __uint_as_float(u & 0xffff0000u); }

// ======================= CSR build =======================
// pass 1: degree histogram + per-edge rank (single atomic pass)
__global__ void k_hist(const int* __restrict__ ei, int* __restrict__ cnt,
                       int* __restrict__ rank) {
    int e = blockIdx.x * 256 + threadIdx.x;
    if (e >= ETOT) return;
    int d = (e < NEDGES) ? ei[NEDGES + e] : e - NEDGES;
    rank[e] = atomicAdd(&cnt[d], 1);
}

__global__ __launch_bounds__(256) void k_scan1(const int* __restrict__ cnt,
                                               int* __restrict__ excl,
                                               int* __restrict__ bsum) {
    __shared__ int tmp[256];
    int t = threadIdx.x;
    int base = blockIdx.x * 1024 + t * 4;
    int v0 = base + 0 < NNODES ? cnt[base + 0] : 0;
    int v1 = base + 1 < NNODES ? cnt[base + 1] : 0;
    int v2 = base + 2 < NNODES ? cnt[base + 2] : 0;
    int v3 = base + 3 < NNODES ? cnt[base + 3] : 0;
    int tot = v0 + v1 + v2 + v3;
    tmp[t] = tot;
    __syncthreads();
    for (int off = 1; off < 256; off <<= 1) {
        int x = (t >= off) ? tmp[t - off] : 0;
        __syncthreads();
        tmp[t] += x;
        __syncthreads();
    }
    int tbase = tmp[t] - tot;
    if (base + 0 < NNODES) excl[base + 0] = tbase;
    if (base + 1 < NNODES) excl[base + 1] = tbase + v0;
    if (base + 2 < NNODES) excl[base + 2] = tbase + v0 + v1;
    if (base + 3 < NNODES) excl[base + 3] = tbase + v0 + v1 + v2;
    if (t == 255) bsum[blockIdx.x] = tmp[255];
}

__global__ void k_scan2(int* __restrict__ bsum) {
    if (threadIdx.x == 0 && blockIdx.x == 0) {
        int acc = 0;
        for (int i = 0; i < NB_SCAN; ++i) { int v = bsum[i]; bsum[i] = acc; acc += v; }
    }
}

// pass 2: final csr position per edge (in-place over rank; no atomics)
__global__ void k_pos(const int* __restrict__ ei, const int* __restrict__ excl,
                      const int* __restrict__ bsum, int* __restrict__ rankpos) {
    int e = blockIdx.x * 256 + threadIdx.x;
    if (e >= ETOT) return;
    int d = (e < NEDGES) ? ei[NEDGES + e] : e - NEDGES;
    rankpos[e] = excl[d] + bsum[d >> 10] + rankpos[e];
}

// pass 3: partitioned scatter. csr is node-ordered, so pos-range <=> contiguous
// csr slice; partition p (= blockIdx&7 -> XCD p via round-robin dispatch) only
// writes its slice => each csr line stays in ONE XCD's L2, written back once.
__global__ __launch_bounds__(256) void k_scatter(const int* __restrict__ ei,
                                                 const int* __restrict__ pos,
                                                 int* __restrict__ csr_src) {
    int p = blockIdx.x & (NPART - 1);
    int chunk = blockIdx.x / NPART;
    int lo = p * PSZ, hi = lo + PSZ;
    int e0 = chunk * SCAT_CH;
    int e1 = e0 + SCAT_CH; if (e1 > ETOT) e1 = ETOT;
    for (int e = e0 + threadIdx.x; e < e1; e += 256) {
        int ps = pos[e];
        if (ps >= lo && ps < hi) {
            int s = (e < NEDGES) ? ei[e] : e - NEDGES;
            csr_src[ps] = s;
        }
    }
}

// ---------------- GEMM1 + fused alphas + bf16 store ----------------
__global__ __launch_bounds__(256) void k_gemm1(const float* __restrict__ x,
                                               const float* __restrict__ W1,
                                               const float* __restrict__ a1s,
                                               const float* __restrict__ a1d,
                                               unsigned short* __restrict__ h1b,
                                               float* __restrict__ as1,
                                               float* __restrict__ ad1) {
    __shared__ float sW[128 * 128];   // 64 KB
    __shared__ float sX[64 * 128];    // 32 KB
    int t = threadIdx.x;
    {
        const float4* W4 = (const float4*)W1;
        float4* sW4 = (float4*)sW;
#pragma unroll
        for (int i = 0; i < 16; ++i) sW4[t + 256 * i] = W4[t + 256 * i];
    }
    int nbase = blockIdx.x * 64;
    int nrows = NNODES - nbase; if (nrows > 64) nrows = 64;
    {
        const float4* X4 = (const float4*)(x + (size_t)nbase * 128);
        float4* sX4 = (float4*)sX;
        for (int i = t; i < nrows * 32; i += 256) sX4[i] = X4[i];
    }
    __syncthreads();

    int colg = t & 31, rowg = t >> 5;
    int c0 = colg * 4, n0 = rowg * 8;
    float acc[8][4];
#pragma unroll
    for (int i = 0; i < 8; ++i)
        acc[i][0] = acc[i][1] = acc[i][2] = acc[i][3] = 0.f;

    for (int k = 0; k < 128; k += 4) {
        float4 w0 = *(const float4*)&sW[(k + 0) * 128 + c0];
        float4 w1 = *(const float4*)&sW[(k + 1) * 128 + c0];
        float4 w2 = *(const float4*)&sW[(k + 2) * 128 + c0];
        float4 w3 = *(const float4*)&sW[(k + 3) * 128 + c0];
#pragma unroll
        for (int i = 0; i < 8; ++i) {
            float4 xv = *(const float4*)&sX[(n0 + i) * 128 + k];
            acc[i][0] = fmaf(xv.x, w0.x, acc[i][0]); acc[i][1] = fmaf(xv.x, w0.y, acc[i][1]);
            acc[i][2] = fmaf(xv.x, w0.z, acc[i][2]); acc[i][3] = fmaf(xv.x, w0.w, acc[i][3]);
            acc[i][0] = fmaf(xv.y, w1.x, acc[i][0]); acc[i][1] = fmaf(xv.y, w1.y, acc[i][1]);
            acc[i][2] = fmaf(xv.y, w1.z, acc[i][2]); acc[i][3] = fmaf(xv.y, w1.w, acc[i][3]);
            acc[i][0] = fmaf(xv.z, w2.x, acc[i][0]); acc[i][1] = fmaf(xv.z, w2.y, acc[i][1]);
            acc[i][2] = fmaf(xv.z, w2.z, acc[i][2]); acc[i][3] = fmaf(xv.z, w2.w, acc[i][3]);
            acc[i][0] = fmaf(xv.w, w3.x, acc[i][0]); acc[i][1] = fmaf(xv.w, w3.y, acc[i][1]);
            acc[i][2] = fmaf(xv.w, w3.z, acc[i][2]); acc[i][3] = fmaf(xv.w, w3.w, acc[i][3]);
        }
    }

    int head = colg >> 3;
    float ws0 = a1s[c0], ws1 = a1s[c0 + 1], ws2 = a1s[c0 + 2], ws3 = a1s[c0 + 3];
    float wd0 = a1d[c0], wd1 = a1d[c0 + 1], wd2 = a1d[c0 + 2], wd3 = a1d[c0 + 3];
#pragma unroll
    for (int i = 0; i < 8; ++i) {
        int n = n0 + i;
        float ps = acc[i][0] * ws0 + acc[i][1] * ws1 + acc[i][2] * ws2 + acc[i][3] * ws3;
        float pd = acc[i][0] * wd0 + acc[i][1] * wd1 + acc[i][2] * wd2 + acc[i][3] * wd3;
        ps += __shfl_xor(ps, 1); ps += __shfl_xor(ps, 2); ps += __shfl_xor(ps, 4);
        pd += __shfl_xor(pd, 1); pd += __shfl_xor(pd, 2); pd += __shfl_xor(pd, 4);
        if (n < nrows) {
            unsigned b0 = f2bf(acc[i][0]), b1 = f2bf(acc[i][1]);
            unsigned b2 = f2bf(acc[i][2]), b3 = f2bf(acc[i][3]);
            uint2 pk; pk.x = b0 | (b1 << 16); pk.y = b2 | (b3 << 16);
            *(uint2*)&h1b[((size_t)(nbase + n)) * 128 + c0] = pk;
            if ((colg & 7) == 0) {
                as1[(size_t)(nbase + n) * 4 + head] = ps;
                ad1[(size_t)(nbase + n) * 4 + head] = pd;
            }
        }
    }
}

// -------- layer-1 aggregation: 32 lanes/node, single pass, postponed division --------
__global__ __launch_bounds__(256) void k_node1(const int* __restrict__ csr_src,
        const int* __restrict__ excl, const int* __restrict__ bsum,
        const int* __restrict__ cnt, const unsigned short* __restrict__ h1b,
        const float4* __restrict__ as1v, const float4* __restrict__ ad1v,
        float* __restrict__ out1) {
    __shared__ float4 exbuf[8][32];
    int t = threadIdx.x;
    int grp = t >> 5, lane = t & 31;
    int node = blockIdx.x * 8 + grp;
    if (node >= NNODES) return;
    int head = lane >> 3;
    int off = excl[node] + bsum[node >> 10];
    int deg = cnt[node];
    float4 adv = ad1v[node];
    float4 dp = make_float4(0.f, 0.f, 0.f, 0.f);
    float4 acc = make_float4(0.f, 0.f, 0.f, 0.f);
    const float* exs = (const float*)&exbuf[grp][0];

    for (int base = 0; base < deg; base += 32) {
        int m = deg - base; if (m > 32) m = 32;
        int sv = 0;
        if (lane < m) {
            sv = csr_src[off + base + lane];
            float4 av = as1v[sv];
            float v; float4 e;
            v = av.x + adv.x; v = v > 0.f ? v : NEG * v; e.x = __expf(v);
            v = av.y + adv.y; v = v > 0.f ? v : NEG * v; e.y = __expf(v);
            v = av.z + adv.z; v = v > 0.f ? v : NEG * v; e.z = __expf(v);
            v = av.w + adv.w; v = v > 0.f ? v : NEG * v; e.w = __expf(v);
            exbuf[grp][lane] = e;
            dp.x += e.x; dp.y += e.y; dp.z += e.z; dp.w += e.w;
        }
        __builtin_amdgcn_wave_barrier();
        for (int i = 0; i < m; ++i) {
            int s = __shfl(sv, i, 32);
            float a = exs[i * 4 + head];
            uint2 hv = *(const uint2*)(h1b + (size_t)s * 128 + lane * 4);
            acc.x = fmaf(bf_lo(hv.x), a, acc.x);
            acc.y = fmaf(bf_hi(hv.x), a, acc.y);
            acc.z = fmaf(bf_lo(hv.y), a, acc.z);
            acc.w = fmaf(bf_hi(hv.y), a, acc.w);
        }
        __builtin_amdgcn_wave_barrier();
    }
#pragma unroll
    for (int msk = 1; msk < 32; msk <<= 1) {
        dp.x += __shfl_xor(dp.x, msk, 32);
        dp.y += __shfl_xor(dp.y, msk, 32);
        dp.z += __shfl_xor(dp.z, msk, 32);
        dp.w += __shfl_xor(dp.w, msk, 32);
    }
    float inv = 1.f / f4get(dp, head);
    float4 o; o.x = acc.x * inv; o.y = acc.y * inv; o.z = acc.z * inv; o.w = acc.w * inv;
    *(float4*)(out1 + (size_t)node * 128 + lane * 4) = o;
}

// ---- GEMM2 + fused alphas2 + bf16 store ----
__global__ __launch_bounds__(256) void k_gemm2(const float* __restrict__ in,
                                               const float* __restrict__ W2,
                                               const float* __restrict__ b1,
                                               const float* __restrict__ a2s,
                                               const float* __restrict__ a2d,
                                               unsigned short* __restrict__ h2b,
                                               float* __restrict__ as2,
                                               float* __restrict__ ad2) {
    __shared__ float sW[128 * 40];
    __shared__ float sX[128 * 132];
    int t = threadIdx.x;
    for (int i = t; i < 128 * 40 / 4; i += 256) ((float4*)sW)[i] = ((const float4*)W2)[i];
    int nbase = blockIdx.x * 128;
    int nrows = NNODES - nbase; if (nrows > 128) nrows = 128;
    {
        const float4* X4 = (const float4*)(in + (size_t)nbase * 128);
        for (int i = t; i < nrows * 32; i += 256) {
            int row = i >> 5, c4 = i & 31;
            float4 v = X4[i];
            float4 bb = *(const float4*)&b1[c4 * 4];
            v.x += bb.x; v.y += bb.y; v.z += bb.z; v.w += bb.w;
            v.x = v.x > 0.f ? v.x : __expf(v.x) - 1.f;
            v.y = v.y > 0.f ? v.y : __expf(v.y) - 1.f;
            v.z = v.z > 0.f ? v.z : __expf(v.z) - 1.f;
            v.w = v.w > 0.f ? v.w : __expf(v.w) - 1.f;
            *(float4*)&sX[row * 132 + c4 * 4] = v;
        }
    }
    __syncthreads();

    int colg = t & 7, nodeg = t >> 3;
    int c0 = colg * 5;
    float acc[4][5];
#pragma unroll
    for (int i = 0; i < 4; ++i)
#pragma unroll
        for (int c = 0; c < 5; ++c) acc[i][c] = 0.f;

    for (int k = 0; k < 128; k += 4) {
        float4 xv[4];
#pragma unroll
        for (int i = 0; i < 4; ++i)
            xv[i] = *(const float4*)&sX[(nodeg + 32 * i) * 132 + k];
#pragma unroll
        for (int j = 0; j < 4; ++j) {
            float w0 = sW[(k + j) * 40 + c0 + 0];
            float w1 = sW[(k + j) * 40 + c0 + 1];
            float w2 = sW[(k + j) * 40 + c0 + 2];
            float w3 = sW[(k + j) * 40 + c0 + 3];
            float w4 = sW[(k + j) * 40 + c0 + 4];
#pragma unroll
            for (int i = 0; i < 4; ++i) {
                float xs = f4get(xv[i], j);
                acc[i][0] = fmaf(xs, w0, acc[i][0]);
                acc[i][1] = fmaf(xs, w1, acc[i][1]);
                acc[i][2] = fmaf(xs, w2, acc[i][2]);
                acc[i][3] = fmaf(xs, w3, acc[i][3]);
                acc[i][4] = fmaf(xs, w4, acc[i][4]);
            }
        }
    }

    float ws0 = a2s[c0], ws1 = a2s[c0 + 1], ws2 = a2s[c0 + 2], ws3 = a2s[c0 + 3], ws4 = a2s[c0 + 4];
    float wd0 = a2d[c0], wd1 = a2d[c0 + 1], wd2 = a2d[c0 + 2], wd3 = a2d[c0 + 3], wd4 = a2d[c0 + 4];
#pragma unroll
    for (int i = 0; i < 4; ++i) {
        int n = nodeg + 32 * i;
        float ps = acc[i][0]*ws0 + acc[i][1]*ws1 + acc[i][2]*ws2 + acc[i][3]*ws3 + acc[i][4]*ws4;
        float pd = acc[i][0]*wd0 + acc[i][1]*wd1 + acc[i][2]*wd2 + acc[i][3]*wd3 + acc[i][4]*wd4;
        ps += __shfl_xor(ps, 1); ps += __shfl_xor(ps, 2); ps += __shfl_xor(ps, 4);
        pd += __shfl_xor(pd, 1); pd += __shfl_xor(pd, 2); pd += __shfl_xor(pd, 4);
        if (n < nrows) {
            unsigned short* hp = h2b + (size_t)(nbase + n) * 40 + c0;
#pragma unroll
            for (int c = 0; c < 5; ++c) hp[c] = f2bf(acc[i][c]);
            if (colg == 0) {
                as2[nbase + n] = ps;
                ad2[nbase + n] = pd;
            }
        }
    }
}

// -------- layer-2 aggregation: 16 lanes/node --------
__global__ __launch_bounds__(256) void k_node2(const int* __restrict__ csr_src,
        const int* __restrict__ excl, const int* __restrict__ bsum,
        const int* __restrict__ cnt, const unsigned short* __restrict__ h2b,
        const float* __restrict__ as2, const float* __restrict__ ad2,
        float* __restrict__ out2) {
    int t = threadIdx.x;
    int grp = t >> 4, lane = t & 15;
    int node = blockIdx.x * 16 + grp;
    if (node >= NNODES) return;
    int off = excl[node] + bsum[node >> 10];
    int deg = cnt[node];
    float adv = ad2[node];
    float dp = 0.f;
    float4 acc = make_float4(0.f, 0.f, 0.f, 0.f);

    for (int base = 0; base < deg; base += 16) {
        int m = deg - base; if (m > 16) m = 16;
        int sv = 0; float ex = 0.f;
        if (lane < m) {
            sv = csr_src[off + base + lane];
            float v = as2[sv] + adv;
            v = v > 0.f ? v : NEG * v;
            ex = __expf(v);
            dp += ex;
        }
        for (int i = 0; i < m; ++i) {
            int s = __shfl(sv, i, 16);
            float a = __shfl(ex, i, 16);
            if (lane < 10) {
                uint2 hv = *(const uint2*)(h2b + (size_t)s * 40 + lane * 4);
                acc.x = fmaf(bf_lo(hv.x), a, acc.x);
                acc.y = fmaf(bf_hi(hv.x), a, acc.y);
                acc.z = fmaf(bf_lo(hv.y), a, acc.z);
                acc.w = fmaf(bf_hi(hv.y), a, acc.w);
            }
        }
    }
#pragma unroll
    for (int msk = 1; msk < 16; msk <<= 1) dp += __shfl_xor(dp, msk, 16);
    float inv = 1.f / dp;
    if (lane < 10) {
        float4 o; o.x = acc.x * inv; o.y = acc.y * inv; o.z = acc.z * inv; o.w = acc.w * inv;
        *(float4*)(out2 + (size_t)node * 40 + lane * 4) = o;
    }
}

// -------- global mean pool --------
__global__ __launch_bounds__(256) void k_pool(const float* __restrict__ out2,
        const int* __restrict__ batch, const float* __restrict__ b2,
        float* __restrict__ out) {
    int g = blockIdx.x;
    int lo, hi;
    { int a = 0, b = NNODES; while (a < b) { int m = (a + b) >> 1; if (batch[m] < g) a = m + 1; else b = m; } lo = a; }
    { int a = lo, b = NNODES; while (a < b) { int m = (a + b) >> 1; if (batch[m] < g + 1) a = m + 1; else b = m; } hi = a; }
    int cnt = hi - lo;
    int t = threadIdx.x;
    float sum = 0.f;
    if (t < 240) {
        int c = t % 40, r = t / 40;
        for (int n = lo + r; n < hi; n += 6) sum += out2[(size_t)n * 40 + c];
    }
    __shared__ float red[240];
    if (t < 240) red[t] = sum;
    __syncthreads();
    if (t < 40) {
        float s2 = red[t] + red[t + 40] + red[t + 80] + red[t + 120] + red[t + 160] + red[t + 200];
        out[g * 40 + t] = cnt > 0 ? (s2 / (float)cnt + b2[t]) : 0.f;
    }
}

extern "C" void kernel_launch(void* const* d_in, const int* in_sizes, int n_in,
                              void* d_out, int out_size, void* d_ws, size_t ws_size,
                              hipStream_t stream) {
    const float* x    = (const float*)d_in[0];
    const int*   ei   = (const int*)d_in[1];
    const int*   batch= (const int*)d_in[2];
    const float* W1   = (const float*)d_in[3];
    const float* a1s  = (const float*)d_in[4];
    const float* a1d  = (const float*)d_in[5];
    const float* b1   = (const float*)d_in[6];
    const float* W2   = (const float*)d_in[7];
    const float* a2s  = (const float*)d_in[8];
    const float* a2d  = (const float*)d_in[9];
    const float* b2   = (const float*)d_in[10];
    float* out = (float*)d_out;

    // ---- workspace layout ----
    int* cnt     = (int*)d_ws;                      // N   (memset 0)
    int* excl    = cnt + NNODES;                    // N
    int* boffs   = excl + NNODES;                   // 128
    int* rankpos = boffs + 128;                     // ETOT (rank, then pos in-place)
    int* csr     = rankpos + ETOT;                  // ETOT
    float* as1   = (float*)(csr + ETOT);            // N*4
    float* ad1   = as1 + (size_t)NNODES * 4;        // N*4
    unsigned short* h1b = (unsigned short*)(ad1 + (size_t)NNODES * 4);  // N*128 bf16
    float* out1  = (float*)(h1b + (size_t)NNODES * 128);                // N*128 f32
    float* as2   = out1 + (size_t)NNODES * 128;     // N
    float* ad2   = as2 + NNODES;                    // N
    unsigned short* h2b = (unsigned short*)(ad2 + NNODES);              // N*40 bf16
    float* out2  = (float*)(h2b + (size_t)NNODES * 40);                 // N*40 f32

    hipMemsetAsync(d_ws, 0, (size_t)NNODES * sizeof(int), stream);

    // CSR build: hist(+rank) -> scan -> pos -> partitioned scatter
    k_hist<<<(ETOT + 255) / 256, 256, 0, stream>>>(ei, cnt, rankpos);
    k_scan1<<<NB_SCAN, 256, 0, stream>>>(cnt, excl, boffs);
    k_scan2<<<1, 64, 0, stream>>>(boffs);
    k_pos<<<(ETOT + 255) / 256, 256, 0, stream>>>(ei, excl, boffs, rankpos);
    k_scatter<<<NPART * SCAT_BPP, 256, 0, stream>>>(ei, rankpos, csr);

    // layer 1
    k_gemm1<<<(NNODES + 63) / 64, 256, 0, stream>>>(x, W1, a1s, a1d, h1b, as1, ad1);
    k_node1<<<(NNODES + 7) / 8, 256, 0, stream>>>(csr, excl, boffs, cnt, h1b,
                                                  (const float4*)as1, (const float4*)ad1, out1);

    // layer 2
    k_gemm2<<<(NNODES + 127) / 128, 256, 0, stream>>>(out1, W2, b1, a2s, a2d, h2b, as2, ad2);
    k_node2<<<(NNODES + 15) / 16, 256, 0, stream>>>(csr, excl, boffs, cnt, h2b, as2, ad2, out2);

    // pool
    k_pool<<<NGRAPH, 256, 0, stream>>>(out2, batch, b2, out);
}